// Round 9
// baseline (649.886 us; speedup 1.0000x reference)
//
#include <hip/hip_runtime.h>
#include <math.h>

#define GH 300
#define GW 400
#define GHW (GH * GW)
#define B1 1024  // fallback staging chunks (unused on main path)
#define Q 16

// finalize_poly: blocks [0, FBLK) finalize cells; blocks [FBLK, ...) do polylines
#define FBLK ((GHW + 1023) / 1024)  // 118

// poly-branch shared memory (R6-verified layout)
#define SMEM_BYTES 41056

// ---------------------------------------------------------------------------
// Shared binning (bit-identical to the verified round-3..9 semantics):
// XLA canonicalization of (x - X0)/RES -> (x + 20) * 10 in f32, no FMA.
// ---------------------------------------------------------------------------
__device__ __forceinline__ bool bin_point(float x, float y, int& px, int& py) {
    if (!(x >= -20.0f && x < 20.0f && y >= -10.0f && y < 30.0f)) return false;
    float qx = __fmul_rn(__fsub_rn(x, -20.0f), 10.0f);
    float qy = __fmul_rn(__fsub_rn(y, -10.0f), 10.0f);
    px = min(max((int)qx, 0), GW - 1);
    py = min(max((int)qy, 0), GH - 1);
    return true;
}

// 1024-thread block exclusive scan (wave64 + 16-wave combine) — poly branch.
__device__ __forceinline__ unsigned block_scan_excl_1024(unsigned c, unsigned* wsum, int l) {
    int lane = l & 63, wid = l >> 6;
    unsigned v = c;
#pragma unroll
    for (int d = 1; d < 64; d <<= 1) {
        unsigned u = __shfl_up(v, d, 64);
        if (lane >= d) v += u;
    }
    if (lane == 63) wsum[wid] = v;
    __syncthreads();
    if (l < 16) {
        unsigned wv = wsum[l], worig = wv;
#pragma unroll
        for (int d = 1; d < 16; d <<= 1) {
            unsigned u = __shfl_up(wv, d, 16);
            if (l >= d) wv += u;
        }
        wsum[l] = wv - worig;  // exclusive wave offset
    }
    __syncthreads();
    return (v - c) + wsum[wid];
}

// ---------------------------------------------------------------------------
// initA: zero the two atomic sink grids (workspace is harness-poisoned every
// iteration) and output channels 3/4. 4 x 480 KB, uint4-vectorized.
// ---------------------------------------------------------------------------
__global__ __launch_bounds__(256) void initA_kernel(unsigned* __restrict__ icg,
                                                    unsigned* __restrict__ zg,
                                                    float* __restrict__ out) {
    const int n4 = GHW / 4;  // 30000
    uint4 z = make_uint4(0u, 0u, 0u, 0u);
    int stride = gridDim.x * 256;
    for (int j = blockIdx.x * 256 + (int)threadIdx.x; j < n4; j += stride) {
        ((uint4*)icg)[j] = z;
        ((uint4*)zg)[j] = z;
        ((uint4*)(out + 3 * GHW))[j] = z;  // f32 0.0 == u32 0
        ((uint4*)(out + 4 * GHW))[j] = z;
    }
}

// ---------------------------------------------------------------------------
// lidarA: ONE pass over the point cloud, direct global atomics into two
// L2-resident u32 grids (480 KB each). Round-8 conclusion: the staged
// 2-pass architecture has a ~40 us floor (4 consumer rewrites all landed
// p2-tile at 22-25 us); direct atomics need only the 64 MB read (~10 us)
// + 5.1M u32 atomics at ~21-per-cell contention (~8-14 us, overlapped).
//   zg[idx]  = max z16   (R4/5-verified quantization; empty cell = 0)
//   icg[idx] = sum of (1<<20)|i8  (R7-verified packing; overflow needs
//              cnt>=4096/cell vs expected 21 +/- 4.6 — impossible here)
// Semantics = verified round-3 atomic path + verified quantizations; integer
// merges are order-free.
// ---------------------------------------------------------------------------
__global__ __launch_bounds__(256) void lidarA_kernel(const float4* __restrict__ pts, int n,
                                                     unsigned* __restrict__ icg,
                                                     unsigned* __restrict__ zg) {
    int stride = gridDim.x * 256;
    for (int i = blockIdx.x * 256 + (int)threadIdx.x; i < n; i += stride) {
        float4 p = pts[i];
        int px, py;
        if (bin_point(p.x, p.y, px, py)) {
            int idx = py * GW + px;
            int z16 = min(max((int)rintf(__fmul_rn(__fadd_rn(p.z, 3.0f), 65535.0f / 7.0f)), 0),
                          65535);
            int i8 = min(max((int)rintf(p.w), 0), 255);
            atomicMax(&zg[idx], (unsigned)z16);
            atomicAdd(&icg[idx], (1u << 20) | (unsigned)i8);
        }
    }
}

// ---------------------------------------------------------------------------
// finalize_poly: blocks [0, FBLK) finalize one cell per thread (coalesced
// reads of icg/zg, writes ch0-2; math byte-identical to the R7-verified
// finalize). Blocks [FBLK, ...): R6-verified FLATTENED polyline raster.
// ---------------------------------------------------------------------------
__global__ __launch_bounds__(1024) void finalize_poly_kernel(const unsigned* __restrict__ icg,
                                                             const unsigned* __restrict__ zg,
                                                             float* __restrict__ out,
                                                             const float2* __restrict__ traj,
                                                             int ntraj,
                                                             const float2* __restrict__ osm,
                                                             int nosm,
                                                             const float* __restrict__ ego) {
    __shared__ char smem[SMEM_BYTES];
    int l = threadIdx.x;

    if (blockIdx.x >= FBLK) {
        // ---------------- flattened polyline branch (round-6 verified) -------
        double* ax_s = (double*)(smem);
        double* ay_s = (double*)(smem + 8192);
        double* dx_s = (double*)(smem + 16384);
        double* dy_s = (double*)(smem + 24576);
        unsigned* cum = (unsigned*)(smem + 32768);   // [1025]
        unsigned* chan = (unsigned*)(smem + 36868);  // [1024]
        unsigned* wsum = (unsigned*)(smem + 40964);  // [16]

        int pb = blockIdx.x - FBLK;
        int seg = pb * 1024 + l;
        int ntseg = ntraj - 1;
        int noseg = nosm - 1;
        int nseg = ntseg + noseg;
        unsigned jobs = 0;
        if (seg < nseg) {
            const float2* pts;
            bool use_ego;
            unsigned ch;
            if (seg < ntseg) {
                pts = traj + seg;
                ch = 3u;
                use_ego = false;
            } else {
                pts = osm + (seg - ntseg);
                ch = 4u;
                use_ego = true;
            }
            float2 P0 = pts[0];
            float2 P1 = pts[1];
            if (use_ego) {
                float yaw = ego[2];
                float cy = cosf(-yaw), sy = sinf(-yaw);
                float ex = ego[0], ey = ego[1];
                float d0x = __fsub_rn(P0.x, ex), d0y = __fsub_rn(P0.y, ey);
                float d1x = __fsub_rn(P1.x, ex), d1y = __fsub_rn(P1.y, ey);
                P0.x = __fsub_rn(__fmul_rn(d0x, cy), __fmul_rn(d0y, sy));
                P0.y = __fadd_rn(__fmul_rn(d0x, sy), __fmul_rn(d0y, cy));
                P1.x = __fsub_rn(__fmul_rn(d1x, cy), __fmul_rn(d1y, sy));
                P1.y = __fadd_rn(__fmul_rn(d1x, sy), __fmul_rn(d1y, cy));
            }
            double ax = trunc(__ddiv_rn(__dadd_rn((double)P0.x, 20.0), 0.1));
            double ay = trunc(__ddiv_rn(__dadd_rn((double)P0.y, 10.0), 0.1));
            double bx = trunc(__ddiv_rn(__dadd_rn((double)P1.x, 20.0), 0.1));
            double by = trunc(__ddiv_rn(__dadd_rn((double)P1.y, 10.0), 0.1));
            bool inA = (ax >= 0.0) && (ax < (double)GW) && (ay >= 0.0) && (ay < (double)GH);
            bool inB = (bx >= 0.0) && (bx < (double)GW) && (by >= 0.0) && (by < (double)GH);
            if (inA || inB) {
                ax = fmin(fmax(ax, 0.0), (double)(GW - 1));
                ay = fmin(fmax(ay, 0.0), (double)(GH - 1));
                bx = fmin(fmax(bx, 0.0), (double)(GW - 1));
                by = fmin(fmax(by, 0.0), (double)(GH - 1));
                double dx = __dsub_rn(bx, ax);
                double dy = __dsub_rn(by, ay);
                double dmax = fmax(fabs(dx), fabs(dy));
                jobs = (unsigned)((int)dmax) + 1u;  // kmax+1
                ax_s[l] = ax;
                ay_s[l] = ay;
                dx_s[l] = dx;
                dy_s[l] = dy;
                chan[l] = ch;
            }
        }
        unsigned excl = block_scan_excl_1024(jobs, wsum, l);
        cum[l] = excl;
        if (l == 1023) cum[1024] = excl + jobs;
        __syncthreads();
        unsigned tot = cum[1024];
        for (unsigned j = l; j < tot; j += 1024) {
            unsigned lo = 0, hi = 1024;  // cum[lo] <= j < cum[hi]
#pragma unroll
            for (int it = 0; it < 10; ++it) {
                unsigned mid = (lo + hi) >> 1;
                if (cum[mid] <= j) lo = mid; else hi = mid;
            }
            int k = (int)(j - cum[lo]);
            double ax = ax_s[lo], ay = ay_s[lo], dx = dx_s[lo], dy = dy_s[lo];
            double dmax = fmax(fabs(dx), fabs(dy));
            double denom = fmax(dmax, 1.0);
            double t = __ddiv_rn(fmin((double)k, dmax), denom);
            double ptx = __dadd_rn(ax, __dmul_rn(t, dx));
            double pty = __dadd_rn(ay, __dmul_rn(t, dy));
            int cx = (int)rint(ptx);  // half-to-even
            int cc = (int)rint(pty);
            float* out_ch = out + (size_t)chan[lo] * GHW;
#pragma unroll
            for (int oy = -1; oy <= 1; ++oy) {
#pragma unroll
                for (int ox = -1; ox <= 1; ++ox) {
                    int xx = cx + ox;
                    int yy = cc + oy;
                    if (xx < 0) xx += GW;  // JAX wraps negatives, drops OOB
                    if (yy < 0) yy += GH;
                    if (xx >= 0 && xx < GW && yy >= 0 && yy < GH) {
                        out_ch[yy * GW + xx] = 1.0f;
                    }
                }
            }
        }
        return;
    }

    // ---------------- finalize branch (R7-verified math) ----------------
    int idx = blockIdx.x * 1024 + l;
    if (idx < GHW) {
        unsigned v2 = icg[idx];
        unsigned zfin = zg[idx];
        const float inv7 = 1.0f / 7.0f;
        const float invlog129 = 1.0f / 4.8598124043616719e+00f;  // 1/log(129)
        float h, ich, dd;
        if (v2 == 0) {
            h = fminf(fmaxf(__fmul_rn(3.0f, inv7), 0.0f), 1.0f);  // empty: clip(3/7)
            ich = 0.0f;
            dd = 0.0f;
        } else {
            unsigned cnt = v2 >> 20;              // exact integer
            float sum8 = (float)(v2 & 0xFFFFFu);  // exact integer
            h = fminf((float)zfin * (1.0f / 65535.0f), 1.0f);  // z16-quantized h
            ich = fminf(__fdiv_rn(sum8, __fmul_rn((float)cnt, 255.0f)), 1.0f);
            dd = fminf(__fmul_rn(log1pf((float)cnt), invlog129), 1.0f);
        }
        out[0 * GHW + idx] = h;
        out[1 * GHW + idx] = ich;
        out[2 * GHW + idx] = dd;
    }
}

// ======================== fallback (round-3) path ==========================
__device__ void do_poly_segment(int seg, const float2* __restrict__ traj, int ntraj,
                                const float2* __restrict__ osm, int nosm,
                                const float* __restrict__ ego, float* __restrict__ out) {
    int ntseg = ntraj - 1;
    int noseg = nosm - 1;
    if (seg >= ntseg + noseg) return;
    const float2* pts;
    float* out_ch;
    bool use_ego;
    if (seg < ntseg) {
        pts = traj + seg;
        out_ch = out + 3 * GHW;
        use_ego = false;
    } else {
        pts = osm + (seg - ntseg);
        out_ch = out + 4 * GHW;
        use_ego = true;
    }
    float2 P0 = pts[0];
    float2 P1 = pts[1];
    if (use_ego) {
        float yaw = ego[2];
        float cy = cosf(-yaw), sy = sinf(-yaw);
        float ex = ego[0], ey = ego[1];
        float d0x = __fsub_rn(P0.x, ex), d0y = __fsub_rn(P0.y, ey);
        float d1x = __fsub_rn(P1.x, ex), d1y = __fsub_rn(P1.y, ey);
        P0.x = __fsub_rn(__fmul_rn(d0x, cy), __fmul_rn(d0y, sy));
        P0.y = __fadd_rn(__fmul_rn(d0x, sy), __fmul_rn(d0y, cy));
        P1.x = __fsub_rn(__fmul_rn(d1x, cy), __fmul_rn(d1y, sy));
        P1.y = __fadd_rn(__fmul_rn(d1x, sy), __fmul_rn(d1y, cy));
    }
    double ax = trunc(__ddiv_rn(__dadd_rn((double)P0.x, 20.0), 0.1));
    double ay = trunc(__ddiv_rn(__dadd_rn((double)P0.y, 10.0), 0.1));
    double bx = trunc(__ddiv_rn(__dadd_rn((double)P1.x, 20.0), 0.1));
    double by = trunc(__ddiv_rn(__dadd_rn((double)P1.y, 10.0), 0.1));
    bool inA = (ax >= 0.0) && (ax < (double)GW) && (ay >= 0.0) && (ay < (double)GH);
    bool inB = (bx >= 0.0) && (bx < (double)GW) && (by >= 0.0) && (by < (double)GH);
    if (!(inA || inB)) return;
    ax = fmin(fmax(ax, 0.0), (double)(GW - 1));
    ay = fmin(fmax(ay, 0.0), (double)(GH - 1));
    bx = fmin(fmax(bx, 0.0), (double)(GW - 1));
    by = fmin(fmax(by, 0.0), (double)(GH - 1));
    double dx = __dsub_rn(bx, ax);
    double dy = __dsub_rn(by, ay);
    double dmax = fmax(fabs(dx), fabs(dy));
    double denom = fmax(dmax, 1.0);
    int kmax = (int)dmax;
    for (int k = 0; k <= kmax; ++k) {
        double t = __ddiv_rn(fmin((double)k, dmax), denom);
        double ptx = __dadd_rn(ax, __dmul_rn(t, dx));
        double pty = __dadd_rn(ay, __dmul_rn(t, dy));
        int cx = (int)rint(ptx);  // half-to-even
        int cc = (int)rint(pty);
#pragma unroll
        for (int oy = -1; oy <= 1; ++oy) {
#pragma unroll
            for (int ox = -1; ox <= 1; ++ox) {
                int xx = cx + ox;
                int yy = cc + oy;
                if (xx < 0) xx += GW;
                if (yy < 0) yy += GH;
                if (xx >= 0 && xx < GW && yy >= 0 && yy < GH) {
                    out_ch[yy * GW + xx] = 1.0f;
                }
            }
        }
    }
}

__global__ __launch_bounds__(256) void init_kernel(float* __restrict__ out) {
    int i = blockIdx.x * blockDim.x + threadIdx.x;
    if (i < GHW) {
        out[0 * GHW + i] = -INFINITY;
        out[1 * GHW + i] = 0.0f;
        out[2 * GHW + i] = 0.0f;
        out[3 * GHW + i] = 0.0f;
        out[4 * GHW + i] = 0.0f;
    }
}

__device__ __forceinline__ void atomicMaxFloat(float* addr, float val) {
    if (val >= 0.0f) {
        atomicMax((int*)addr, __float_as_int(val));
    } else {
        atomicMin((unsigned int*)addr, (unsigned int)__float_as_int(val));
    }
}

__global__ __launch_bounds__(256) void lidar_kernel(const float4* __restrict__ pts, int n,
                                                    float* __restrict__ out) {
    int i = blockIdx.x * blockDim.x + threadIdx.x;
    if (i >= n) return;
    float4 p = pts[i];
    int px, py;
    if (!bin_point(p.x, p.y, px, py)) return;
    int idx = py * GW + px;
    atomicMaxFloat(&out[0 * GHW + idx], p.z);
    atomicAdd(&out[1 * GHW + idx], p.w);
    atomicAdd(&out[2 * GHW + idx], 1.0f);
}

__global__ __launch_bounds__(256) void finalize_kernel(float* __restrict__ out) {
    int i = blockIdx.x * blockDim.x + threadIdx.x;
    if (i >= GHW) return;
    float hm = out[0 * GHW + i];
    float isum = out[1 * GHW + i];
    float c = out[2 * GHW + i];
    if (hm == -INFINITY) hm = 0.0f;
    const float inv7 = 1.0f / 7.0f;
    const float inv255 = 1.0f / 255.0f;
    const float invlog129 = 1.0f / 4.8598124043616719e+00f;
    float h = fminf(fmaxf(__fmul_rn(__fadd_rn(hm, 3.0f), inv7), 0.0f), 1.0f);
    float im = (c > 0.0f) ? __fdiv_rn(isum, fmaxf(c, 1.0f)) : 0.0f;
    float ich = fminf(fmaxf(__fmul_rn(im, inv255), 0.0f), 1.0f);
    float dd = fminf(fmaxf(__fmul_rn(log1pf(c), invlog129), 0.0f), 1.0f);
    out[0 * GHW + i] = h;
    out[1 * GHW + i] = ich;
    out[2 * GHW + i] = dd;
}

__global__ __launch_bounds__(256) void polylines_kernel(const float2* __restrict__ traj,
                                                        int ntraj,
                                                        const float2* __restrict__ osm, int nosm,
                                                        const float* __restrict__ ego,
                                                        float* __restrict__ out) {
    int seg = blockIdx.x * 256 + (int)threadIdx.x;
    do_poly_segment(seg, traj, ntraj, osm, nosm, ego, out);
}

extern "C" void kernel_launch(void* const* d_in, const int* in_sizes, int n_in,
                              void* d_out, int out_size, void* d_ws, size_t ws_size,
                              hipStream_t stream) {
    const float* lidar = (const float*)d_in[0];
    const float* traj = (const float*)d_in[1];
    const float* osm = (const float*)d_in[2];
    const float* ego = (const float*)d_in[3];
    float* out = (float*)d_out;

    int n_lidar = in_sizes[0] / 4;
    int n_traj = in_sizes[1] / 2;
    int n_osm = in_sizes[2] / 2;
    int nseg = (n_traj - 1) + (n_osm - 1);
    int npb = (nseg + 1023) / 1024;  // poly blocks: 1024 segments each

    size_t need = (size_t)2 * GHW * 4;  // icg + zg (960 KB)

    if (ws_size >= need) {
        char* w = (char*)d_ws;
        unsigned* icg = (unsigned*)w;
        unsigned* zg = (unsigned*)(w + (size_t)GHW * 4);

        // ~8 points/thread grid-stride for the atomic pass
        int nbl = (n_lidar + 2047) / 2048;
        if (nbl > 4096) nbl = 4096;
        if (nbl < 256) nbl = 256;

        initA_kernel<<<256, 256, 0, stream>>>(icg, zg, out);
        lidarA_kernel<<<nbl, 256, 0, stream>>>((const float4*)lidar, n_lidar, icg, zg);
        finalize_poly_kernel<<<FBLK + npb, 1024, 0, stream>>>(icg, zg, out,
                                                              (const float2*)traj, n_traj,
                                                              (const float2*)osm, n_osm, ego);
    } else {
        // fallback: verified round-3 atomic path
        init_kernel<<<(GHW + 255) / 256, 256, 0, stream>>>(out);
        lidar_kernel<<<(n_lidar + 255) / 256, 256, 0, stream>>>((const float4*)lidar, n_lidar,
                                                                out);
        finalize_kernel<<<(GHW + 255) / 256, 256, 0, stream>>>(out);
        polylines_kernel<<<(nseg + 255) / 256, 256, 0, stream>>>((const float2*)traj, n_traj,
                                                                 (const float2*)osm, n_osm, ego,
                                                                 out);
    }
}

// Round 10
// 129.827 us; speedup vs baseline: 5.0058x; 5.0058x over previous
//
#include <hip/hip_runtime.h>
#include <math.h>

#define GH 300
#define GW 400
#define GHW (GH * GW)

// Tile grid: 16x16 cells per tile
#define TCOLS 25                 // 400/16
#define TROWS 19                 // ceil(300/16)
#define T_TILES (TCOLS * TROWS)  // 475
#define B1 1024                  // P1 blocks / staging chunks
#define Q 16                     // per-thread LDS record quota (per_block <= 4096)
#define CAP2 8192                // p2 record batch (32 KB LDS); expected ~5.4K/tile

// p2 shared-memory overlay (tile branch and poly branch are different blocks):
//  tile: addr u32[8192] @0 | cumB u32[1025] @32768 | wsum u32[16] @36868 |
//        ic4 u32[4][256] @36932 | zmax4 u32[4][256] @41028   (45124 B)
//  poly: ax,ay,dx,dy dbl[1024] @0/8192/16384/24576 | cum u32[1025] @32768 |
//        chan u32[1024] @36868 | wsum u32[16] @40964  (41028 B)
#define SMEM_BYTES 45152

// ---------------------------------------------------------------------------
// Shared binning (bit-identical to the verified round-3..9 semantics):
// XLA canonicalization of (x - X0)/RES -> (x + 20) * 10 in f32, no FMA.
// ---------------------------------------------------------------------------
__device__ __forceinline__ bool bin_point(float x, float y, int& px, int& py) {
    if (!(x >= -20.0f && x < 20.0f && y >= -10.0f && y < 30.0f)) return false;
    float qx = __fmul_rn(__fsub_rn(x, -20.0f), 10.0f);
    float qy = __fmul_rn(__fsub_rn(y, -10.0f), 10.0f);
    px = min(max((int)qx, 0), GW - 1);
    py = min(max((int)qy, 0), GH - 1);
    return true;
}

// Wave-0 exclusive scan of src[0..T_TILES) into dst[0..T_TILES] (dst[T_TILES]=total).
__device__ __forceinline__ void tile_prefix_wave0(const unsigned* src, unsigned* dst) {
    int lane = threadIdx.x;
    if (lane < 64) {
        unsigned run = 0;
        for (int c = 0; c < T_TILES; c += 64) {
            int idx = c + lane;
            unsigned v = (idx < T_TILES) ? src[idx] : 0u;
            unsigned orig = v;
#pragma unroll
            for (int d = 1; d < 64; d <<= 1) {
                unsigned u = __shfl_up(v, d, 64);
                if (lane >= d) v += u;
            }
            if (idx < T_TILES) dst[idx] = run + (v - orig);  // exclusive
            run += __shfl(v, 63, 64);
        }
        if (lane == 0) dst[T_TILES] = run;
    }
}

// 1024-thread block exclusive scan (wave64 + 16-wave combine), used by p2.
__device__ __forceinline__ unsigned block_scan_excl_1024(unsigned c, unsigned* wsum, int l) {
    int lane = l & 63, wid = l >> 6;
    unsigned v = c;
#pragma unroll
    for (int d = 1; d < 64; d <<= 1) {
        unsigned u = __shfl_up(v, d, 64);
        if (lane >= d) v += u;
    }
    if (lane == 63) wsum[wid] = v;
    __syncthreads();
    if (l < 16) {
        unsigned wv = wsum[l], worig = wv;
#pragma unroll
        for (int d = 1; d < 16; d <<= 1) {
            unsigned u = __shfl_up(wv, d, 16);
            if (l >= d) wv += u;
        }
        wsum[l] = wv - worig;  // exclusive wave offset
    }
    __syncthreads();
    return (v - c) + wsum[wid];
}

// Record (u32): [z16 : 16] | [i8 : 8] | [local8 : 0]   (tile implicit via pref_t)
//   z16 = round((z+3)*65535/7) clamped — h quantization err 7.6e-6 (R4/5-verified)
//   i8  = round(inten) clamped [0,255] — adds <= 0.5/255 ~ 2e-3 to ich (tol 2e-2)
__device__ __forceinline__ bool make_record(float4 p, unsigned& rec, int& tile) {
    int px, py;
    if (!bin_point(p.x, p.y, px, py)) return false;
    tile = (py >> 4) * TCOLS + (px >> 4);
    int local = ((py & 15) << 4) | (px & 15);
    int z16 = min(max((int)rintf(__fmul_rn(__fadd_rn(p.z, 3.0f), 65535.0f / 7.0f)), 0), 65535);
    int i8 = min(max((int)rintf(p.w), 0), 255);
    rec = ((unsigned)z16 << 16) | ((unsigned)i8 << 8) | (unsigned)local;
    return true;
}

// ---------------------------------------------------------------------------
// P1: fused hist + local-sort + staged scatter. One read of the point cloud.
// R9 change (only): the counting-sort permutation now lands in a block-local
// LDS buffer (sbuf[pos]) and the chunk is written out with COALESCED uint4
// stores — replacing 2.56M fully address-divergent 4B global lane-stores
// (~64 TA-cycles/wave) with ~1K 16B wave-stores per block. per_block is
// rounded to x4 on host so chunk bases are 16B-aligned. Record values,
// per-(block,tile) grouping, and pref_t are byte-identical to R7; within-run
// order remains atomic-arrival (merges are order-free integer ops).
// Tail slots [nrec, ceil4(nrec)) hold garbage but lie beyond every pref
// range — never read by p2.
// ---------------------------------------------------------------------------
__global__ __launch_bounds__(256) void p1_kernel(const float4* __restrict__ pts, int n,
                                                 int per_block,
                                                 unsigned* __restrict__ staged,
                                                 unsigned* __restrict__ pref_t,
                                                 float* __restrict__ out) {
    __shared__ unsigned lbuf[256 * Q];        // transposed [j*256+tid]
    __shared__ unsigned short ltile[256 * Q];
    __shared__ unsigned sbuf[256 * Q];        // block-local sorted records
    __shared__ unsigned cnt[T_TILES];
    __shared__ unsigned pref[T_TILES + 1];
    __shared__ unsigned cur[T_TILES];
    for (int t = threadIdx.x; t < T_TILES; t += 256) cnt[t] = 0;
    // zero ch3/ch4 (polyline stamps run in P2, stream-ordered after P1)
    float4* z4 = (float4*)(out + 3 * GHW);
    for (int j = blockIdx.x * 256 + (int)threadIdx.x; j < (2 * GHW) / 4; j += B1 * 256)
        z4[j] = make_float4(0.0f, 0.0f, 0.0f, 0.0f);
    __syncthreads();

    int start = blockIdx.x * per_block;
    int end = min(start + per_block, n);
    int nmine = 0;
    int i = start + (int)threadIdx.x;
    for (; i + 7 * 256 < end; i += 8 * 256) {
        float4 p[8];
#pragma unroll
        for (int j = 0; j < 8; ++j) p[j] = pts[i + j * 256];
#pragma unroll
        for (int j = 0; j < 8; ++j) {
            unsigned r;
            int tile;
            if (make_record(p[j], r, tile)) {
                lbuf[nmine * 256 + threadIdx.x] = r;
                ltile[nmine * 256 + threadIdx.x] = (unsigned short)tile;
                ++nmine;
                atomicAdd(&cnt[tile], 1u);
            }
        }
    }
    for (; i + 3 * 256 < end; i += 4 * 256) {
        float4 p[4];
#pragma unroll
        for (int j = 0; j < 4; ++j) p[j] = pts[i + j * 256];
#pragma unroll
        for (int j = 0; j < 4; ++j) {
            unsigned r;
            int tile;
            if (make_record(p[j], r, tile)) {
                lbuf[nmine * 256 + threadIdx.x] = r;
                ltile[nmine * 256 + threadIdx.x] = (unsigned short)tile;
                ++nmine;
                atomicAdd(&cnt[tile], 1u);
            }
        }
    }
    for (; i < end; i += 256) {
        unsigned r;
        int tile;
        if (make_record(pts[i], r, tile)) {
            lbuf[nmine * 256 + threadIdx.x] = r;
            ltile[nmine * 256 + threadIdx.x] = (unsigned short)tile;
            ++nmine;
            atomicAdd(&cnt[tile], 1u);
        }
    }
    __syncthreads();
    tile_prefix_wave0(cnt, pref);
    __syncthreads();
    for (int t = threadIdx.x; t < T_TILES; t += 256) cur[t] = pref[t];
    for (int t = threadIdx.x; t <= T_TILES; t += 256)
        pref_t[t * B1 + blockIdx.x] = pref[t];
    __syncthreads();
    // LDS counting-sort scatter (replaces divergent global scatter)
    for (int j = 0; j < nmine; ++j) {
        unsigned r = lbuf[j * 256 + threadIdx.x];
        int tile = (int)ltile[j * 256 + threadIdx.x];
        unsigned pos = atomicAdd(&cur[tile], 1u);  // pos < per_block <= 4096
        sbuf[pos] = r;
    }
    __syncthreads();
    // coalesced 16B write-out of the sorted chunk (base 16B-aligned: per_block % 4 == 0)
    unsigned nrec = pref[T_TILES];
    unsigned nw4 = (nrec + 3u) >> 2;
    uint4* dst = (uint4*)(staged + (size_t)blockIdx.x * (size_t)per_block);
    const uint4* src = (const uint4*)sbuf;
    for (unsigned k = threadIdx.x; k < nw4; k += 256) dst[k] = src[k];
}

// ---------------------------------------------------------------------------
// Polyline segment rasterizer, thread-per-segment (byte-identical math to the
// verified R3..R9 path). Used by the FALLBACK path only.
// ---------------------------------------------------------------------------
__device__ void do_poly_segment(int seg, const float2* __restrict__ traj, int ntraj,
                                const float2* __restrict__ osm, int nosm,
                                const float* __restrict__ ego, float* __restrict__ out) {
    int ntseg = ntraj - 1;
    int noseg = nosm - 1;
    if (seg >= ntseg + noseg) return;
    const float2* pts;
    float* out_ch;
    bool use_ego;
    if (seg < ntseg) {
        pts = traj + seg;
        out_ch = out + 3 * GHW;
        use_ego = false;
    } else {
        pts = osm + (seg - ntseg);
        out_ch = out + 4 * GHW;
        use_ego = true;
    }
    float2 P0 = pts[0];
    float2 P1 = pts[1];
    if (use_ego) {
        float yaw = ego[2];
        float cy = cosf(-yaw), sy = sinf(-yaw);
        float ex = ego[0], ey = ego[1];
        float d0x = __fsub_rn(P0.x, ex), d0y = __fsub_rn(P0.y, ey);
        float d1x = __fsub_rn(P1.x, ex), d1y = __fsub_rn(P1.y, ey);
        P0.x = __fsub_rn(__fmul_rn(d0x, cy), __fmul_rn(d0y, sy));
        P0.y = __fadd_rn(__fmul_rn(d0x, sy), __fmul_rn(d0y, cy));
        P1.x = __fsub_rn(__fmul_rn(d1x, cy), __fmul_rn(d1y, sy));
        P1.y = __fadd_rn(__fmul_rn(d1x, sy), __fmul_rn(d1y, cy));
    }
    double ax = trunc(__ddiv_rn(__dadd_rn((double)P0.x, 20.0), 0.1));
    double ay = trunc(__ddiv_rn(__dadd_rn((double)P0.y, 10.0), 0.1));
    double bx = trunc(__ddiv_rn(__dadd_rn((double)P1.x, 20.0), 0.1));
    double by = trunc(__ddiv_rn(__dadd_rn((double)P1.y, 10.0), 0.1));
    bool inA = (ax >= 0.0) && (ax < (double)GW) && (ay >= 0.0) && (ay < (double)GH);
    bool inB = (bx >= 0.0) && (bx < (double)GW) && (by >= 0.0) && (by < (double)GH);
    if (!(inA || inB)) return;
    ax = fmin(fmax(ax, 0.0), (double)(GW - 1));
    ay = fmin(fmax(ay, 0.0), (double)(GH - 1));
    bx = fmin(fmax(bx, 0.0), (double)(GW - 1));
    by = fmin(fmax(by, 0.0), (double)(GH - 1));
    double dx = __dsub_rn(bx, ax);
    double dy = __dsub_rn(by, ay);
    double dmax = fmax(fabs(dx), fabs(dy));
    double denom = fmax(dmax, 1.0);
    int kmax = (int)dmax;
    for (int k = 0; k <= kmax; ++k) {
        double t = __ddiv_rn(fmin((double)k, dmax), denom);
        double ptx = __dadd_rn(ax, __dmul_rn(t, dx));
        double pty = __dadd_rn(ay, __dmul_rn(t, dy));
        int cx = (int)rint(ptx);  // half-to-even
        int cc = (int)rint(pty);
#pragma unroll
        for (int oy = -1; oy <= 1; ++oy) {
#pragma unroll
            for (int ox = -1; ox <= 1; ++ox) {
                int xx = cx + ox;
                int yy = cc + oy;
                if (xx < 0) xx += GW;  // JAX wraps negatives, drops OOB
                if (yy < 0) yy += GH;
                if (xx >= 0 && xx < GW && yy >= 0 && yy < GH) {
                    out_ch[yy * GW + xx] = 1.0f;
                }
            }
        }
    }
}

// ---------------------------------------------------------------------------
// P2 (VERBATIM the round-7 verified 128.5-us kernel): blocks [0, T_TILES)
// reduce one tile each via addr-expansion + 8-slot MLP gather + 4-replica
// privatized u32 accumulator; blocks [T_TILES, ...) run the R6-verified
// flattened polyline rasterization.
// ---------------------------------------------------------------------------
__global__ __launch_bounds__(1024) void p2_kernel(const unsigned* __restrict__ staged,
                                                  const unsigned* __restrict__ pref_t,
                                                  int per_block,
                                                  float* __restrict__ out,
                                                  const float2* __restrict__ traj, int ntraj,
                                                  const float2* __restrict__ osm, int nosm,
                                                  const float* __restrict__ ego) {
    __shared__ char smem[SMEM_BYTES];
    int l = threadIdx.x;

    if (blockIdx.x >= T_TILES) {
        // ---------------- flattened polyline branch (round-6 verified) -------
        double* ax_s = (double*)(smem);
        double* ay_s = (double*)(smem + 8192);
        double* dx_s = (double*)(smem + 16384);
        double* dy_s = (double*)(smem + 24576);
        unsigned* cum = (unsigned*)(smem + 32768);   // [1025]
        unsigned* chan = (unsigned*)(smem + 36868);  // [1024]
        unsigned* wsum = (unsigned*)(smem + 40964);  // [16]

        int pb = blockIdx.x - T_TILES;
        int seg = pb * 1024 + l;
        int ntseg = ntraj - 1;
        int noseg = nosm - 1;
        int nseg = ntseg + noseg;
        unsigned jobs = 0;
        if (seg < nseg) {
            const float2* pts;
            bool use_ego;
            unsigned ch;
            if (seg < ntseg) {
                pts = traj + seg;
                ch = 3u;
                use_ego = false;
            } else {
                pts = osm + (seg - ntseg);
                ch = 4u;
                use_ego = true;
            }
            float2 P0 = pts[0];
            float2 P1 = pts[1];
            if (use_ego) {
                float yaw = ego[2];
                float cy = cosf(-yaw), sy = sinf(-yaw);
                float ex = ego[0], ey = ego[1];
                float d0x = __fsub_rn(P0.x, ex), d0y = __fsub_rn(P0.y, ey);
                float d1x = __fsub_rn(P1.x, ex), d1y = __fsub_rn(P1.y, ey);
                P0.x = __fsub_rn(__fmul_rn(d0x, cy), __fmul_rn(d0y, sy));
                P0.y = __fadd_rn(__fmul_rn(d0x, sy), __fmul_rn(d0y, cy));
                P1.x = __fsub_rn(__fmul_rn(d1x, cy), __fmul_rn(d1y, sy));
                P1.y = __fadd_rn(__fmul_rn(d1x, sy), __fmul_rn(d1y, cy));
            }
            double ax = trunc(__ddiv_rn(__dadd_rn((double)P0.x, 20.0), 0.1));
            double ay = trunc(__ddiv_rn(__dadd_rn((double)P0.y, 10.0), 0.1));
            double bx = trunc(__ddiv_rn(__dadd_rn((double)P1.x, 20.0), 0.1));
            double by = trunc(__ddiv_rn(__dadd_rn((double)P1.y, 10.0), 0.1));
            bool inA = (ax >= 0.0) && (ax < (double)GW) && (ay >= 0.0) && (ay < (double)GH);
            bool inB = (bx >= 0.0) && (bx < (double)GW) && (by >= 0.0) && (by < (double)GH);
            if (inA || inB) {
                ax = fmin(fmax(ax, 0.0), (double)(GW - 1));
                ay = fmin(fmax(ay, 0.0), (double)(GH - 1));
                bx = fmin(fmax(bx, 0.0), (double)(GW - 1));
                by = fmin(fmax(by, 0.0), (double)(GH - 1));
                double dx = __dsub_rn(bx, ax);
                double dy = __dsub_rn(by, ay);
                double dmax = fmax(fabs(dx), fabs(dy));
                jobs = (unsigned)((int)dmax) + 1u;  // kmax+1
                ax_s[l] = ax;
                ay_s[l] = ay;
                dx_s[l] = dx;
                dy_s[l] = dy;
                chan[l] = ch;
            }
        }
        unsigned excl = block_scan_excl_1024(jobs, wsum, l);
        cum[l] = excl;
        if (l == 1023) cum[1024] = excl + jobs;
        __syncthreads();
        unsigned tot = cum[1024];
        for (unsigned j = l; j < tot; j += 1024) {
            unsigned lo = 0, hi = 1024;  // cum[lo] <= j < cum[hi]
#pragma unroll
            for (int it = 0; it < 10; ++it) {
                unsigned mid = (lo + hi) >> 1;
                if (cum[mid] <= j) lo = mid; else hi = mid;
            }
            int k = (int)(j - cum[lo]);
            double ax = ax_s[lo], ay = ay_s[lo], dx = dx_s[lo], dy = dy_s[lo];
            double dmax = fmax(fabs(dx), fabs(dy));
            double denom = fmax(dmax, 1.0);
            double t = __ddiv_rn(fmin((double)k, dmax), denom);
            double ptx = __dadd_rn(ax, __dmul_rn(t, dx));
            double pty = __dadd_rn(ay, __dmul_rn(t, dy));
            int cx = (int)rint(ptx);  // half-to-even
            int cc = (int)rint(pty);
            float* out_ch = out + (size_t)chan[lo] * GHW;
#pragma unroll
            for (int oy = -1; oy <= 1; ++oy) {
#pragma unroll
                for (int ox = -1; ox <= 1; ++ox) {
                    int xx = cx + ox;
                    int yy = cc + oy;
                    if (xx < 0) xx += GW;  // JAX wraps negatives, drops OOB
                    if (yy < 0) yy += GH;
                    if (xx >= 0 && xx < GW && yy >= 0 && yy < GH) {
                        out_ch[yy * GW + xx] = 1.0f;
                    }
                }
            }
        }
        return;
    }

    // ---------------- tile branch (R7-verified privatized accumulator) -----
    unsigned* addr_lds = (unsigned*)(smem);                // [CAP2] @0
    unsigned* cumB = (unsigned*)(smem + 32768);            // [B1+1]
    unsigned* wsum = (unsigned*)(smem + 36868);            // [16]
    unsigned* ic4 = (unsigned*)(smem + 36932);             // [4][256] (cnt<<20)|sum
    unsigned* zmax4 = (unsigned*)(smem + 41028);           // [4][256]
    // zero all 4 replicas (1024 threads cover 4*256 exactly)
    ic4[l] = 0;
    zmax4[l] = 0;

    // Bijective XCD-contiguous tile mapping (verified round-2/4/5/6/7).
    int bid = blockIdx.x;
    const int NX = 8;
    const int q = T_TILES / NX;  // 59
    const int r = T_TILES % NX;  // 3
    int xk = bid % NX;
    int jj = bid / NX;
    int t = (xk < r ? xk * (q + 1) : r * (q + 1) + (xk - r) * q) + jj;

    // per-chunk counts (coalesced row loads) + block scan -> cumB
    unsigned a0 = pref_t[t * B1 + l];
    unsigned a1 = pref_t[(t + 1) * B1 + l];
    unsigned c = a1 - a0;
    unsigned myBase = block_scan_excl_1024(c, wsum, l);  // barriers cover zero-init
    cumB[l] = myBase;
    if (l == B1 - 1) cumB[B1] = myBase + c;
    __syncthreads();
    unsigned nrec = cumB[B1];
    unsigned myAddr0 = (unsigned)l * (unsigned)per_block + a0;  // < 4.1M, u32-safe
    unsigned* icR = ic4 + ((l >> 6) & 3) * 256;    // wave w -> replica w&3
    unsigned* zmR = zmax4 + ((l >> 6) & 3) * 256;

    // batched expansion + 8-way MLP gather / privatized accumulate
    for (unsigned b0 = 0; b0 < nrec; b0 += CAP2) {
        unsigned bh = min(b0 + CAP2, nrec);
        unsigned j0 = max(myBase, b0);
        unsigned j1 = min(myBase + c, bh);
        for (unsigned j = j0; j < j1; ++j)
            addr_lds[j - b0] = myAddr0 + (j - myBase);
        __syncthreads();
        unsigned nb = bh - b0;
        unsigned ad[8], rr[8];
        bool val[8];
#pragma unroll
        for (int i2 = 0; i2 < 8; ++i2) {
            unsigned ki = (unsigned)l + (unsigned)(i2 * 1024);
            val[i2] = ki < nb;
            ad[i2] = val[i2] ? addr_lds[ki] : 0u;
        }
#pragma unroll
        for (int i2 = 0; i2 < 8; ++i2) {
            if (val[i2]) rr[i2] = staged[ad[i2]];  // independent loads in flight
        }
#pragma unroll
        for (int i2 = 0; i2 < 8; ++i2) {
            if (val[i2]) {
                unsigned r2 = rr[i2];
                int local = (int)(r2 & 255u);
                atomicMax(&zmR[local], r2 >> 16);
                atomicAdd(&icR[local], (1u << 20) | ((r2 >> 8) & 255u));
            }
        }
        __syncthreads();  // addr_lds reuse fence + pre-finalize fence
    }

    // Inline finalize — merge 4 replicas; math byte-identical to verified p2b.
    if (l < 256) {
        unsigned v2 = ic4[l] + ic4[256 + l] + ic4[512 + l] + ic4[768 + l];
        unsigned zfin = max(max(zmax4[l], zmax4[256 + l]),
                            max(zmax4[512 + l], zmax4[768 + l]));
        int trow = t / TCOLS, tcol = t % TCOLS;
        int gy = trow * 16 + (l >> 4);
        int gx = tcol * 16 + (l & 15);
        if (gy < GH) {
            const float inv7 = 1.0f / 7.0f;
            const float invlog129 = 1.0f / 4.8598124043616719e+00f;  // 1/log(129)
            float h, ich, dd;
            if (v2 == 0) {
                h = fminf(fmaxf(__fmul_rn(3.0f, inv7), 0.0f), 1.0f);  // empty: clip(3/7)
                ich = 0.0f;
                dd = 0.0f;
            } else {
                unsigned cnt = v2 >> 20;                     // exact integer
                float sum8 = (float)(v2 & 0xFFFFFu);         // exact integer
                h = fminf((float)zfin * (1.0f / 65535.0f), 1.0f);   // z16-quantized h
                ich = fminf(__fdiv_rn(sum8, __fmul_rn((float)cnt, 255.0f)), 1.0f);
                dd = fminf(__fmul_rn(log1pf((float)cnt), invlog129), 1.0f);
            }
            int idx = gy * GW + gx;
            out[0 * GHW + idx] = h;
            out[1 * GHW + idx] = ich;
            out[2 * GHW + idx] = dd;
        }
    }
}

// Standalone polyline kernel (fallback path).
__global__ __launch_bounds__(256) void polylines_kernel(const float2* __restrict__ traj,
                                                        int ntraj,
                                                        const float2* __restrict__ osm, int nosm,
                                                        const float* __restrict__ ego,
                                                        float* __restrict__ out) {
    int seg = blockIdx.x * 256 + (int)threadIdx.x;
    do_poly_segment(seg, traj, ntraj, osm, nosm, ego, out);
}

// ======================== fallback (round-3) path ==========================
__global__ __launch_bounds__(256) void init_kernel(float* __restrict__ out) {
    int i = blockIdx.x * blockDim.x + threadIdx.x;
    if (i < GHW) {
        out[0 * GHW + i] = -INFINITY;
        out[1 * GHW + i] = 0.0f;
        out[2 * GHW + i] = 0.0f;
        out[3 * GHW + i] = 0.0f;
        out[4 * GHW + i] = 0.0f;
    }
}

__device__ __forceinline__ void atomicMaxFloat(float* addr, float val) {
    if (val >= 0.0f) {
        atomicMax((int*)addr, __float_as_int(val));
    } else {
        atomicMin((unsigned int*)addr, (unsigned int)__float_as_int(val));
    }
}

__global__ __launch_bounds__(256) void lidar_kernel(const float4* __restrict__ pts, int n,
                                                    float* __restrict__ out) {
    int i = blockIdx.x * blockDim.x + threadIdx.x;
    if (i >= n) return;
    float4 p = pts[i];
    int px, py;
    if (!bin_point(p.x, p.y, px, py)) return;
    int idx = py * GW + px;
    atomicMaxFloat(&out[0 * GHW + idx], p.z);
    atomicAdd(&out[1 * GHW + idx], p.w);
    atomicAdd(&out[2 * GHW + idx], 1.0f);
}

__global__ __launch_bounds__(256) void finalize_kernel(float* __restrict__ out) {
    int i = blockIdx.x * blockDim.x + threadIdx.x;
    if (i >= GHW) return;
    float hm = out[0 * GHW + i];
    float isum = out[1 * GHW + i];
    float c = out[2 * GHW + i];
    if (hm == -INFINITY) hm = 0.0f;
    const float inv7 = 1.0f / 7.0f;
    const float inv255 = 1.0f / 255.0f;
    const float invlog129 = 1.0f / 4.8598124043616719e+00f;
    float h = fminf(fmaxf(__fmul_rn(__fadd_rn(hm, 3.0f), inv7), 0.0f), 1.0f);
    float im = (c > 0.0f) ? __fdiv_rn(isum, fmaxf(c, 1.0f)) : 0.0f;
    float ich = fminf(fmaxf(__fmul_rn(im, inv255), 0.0f), 1.0f);
    float dd = fminf(fmaxf(__fmul_rn(log1pf(c), invlog129), 0.0f), 1.0f);
    out[0 * GHW + i] = h;
    out[1 * GHW + i] = ich;
    out[2 * GHW + i] = dd;
}

extern "C" void kernel_launch(void* const* d_in, const int* in_sizes, int n_in,
                              void* d_out, int out_size, void* d_ws, size_t ws_size,
                              hipStream_t stream) {
    const float* lidar = (const float*)d_in[0];
    const float* traj = (const float*)d_in[1];
    const float* osm = (const float*)d_in[2];
    const float* ego = (const float*)d_in[3];
    float* out = (float*)d_out;

    int n_lidar = in_sizes[0] / 4;
    int n_traj = in_sizes[1] / 2;
    int n_osm = in_sizes[2] / 2;
    int nseg = (n_traj - 1) + (n_osm - 1);
    int npb = (nseg + 1023) / 1024;  // p2 poly blocks: 1024 segments each

    int per_block = (n_lidar + B1 - 1) / B1;
    per_block = (per_block + 3) & ~3;  // 16B-align chunk bases for uint4 write-out
    size_t staged_bytes = (size_t)B1 * (size_t)per_block * 4;
    size_t pref_bytes = (size_t)(T_TILES + 1) * B1 * 4;
    size_t need = staged_bytes + pref_bytes;

    if (ws_size >= need && per_block <= 256 * Q) {
        char* w = (char*)d_ws;
        unsigned* staged = (unsigned*)w;
        unsigned* pref_t = (unsigned*)(w + staged_bytes);

        p1_kernel<<<B1, 256, 0, stream>>>((const float4*)lidar, n_lidar, per_block, staged,
                                          pref_t, out);
        p2_kernel<<<T_TILES + npb, 1024, 0, stream>>>(staged, pref_t, per_block, out,
                                                      (const float2*)traj, n_traj,
                                                      (const float2*)osm, n_osm, ego);
    } else {
        // fallback: verified round-3 atomic path
        init_kernel<<<(GHW + 255) / 256, 256, 0, stream>>>(out);
        lidar_kernel<<<(n_lidar + 255) / 256, 256, 0, stream>>>((const float4*)lidar, n_lidar,
                                                                out);
        finalize_kernel<<<(GHW + 255) / 256, 256, 0, stream>>>(out);
        polylines_kernel<<<(nseg + 255) / 256, 256, 0, stream>>>((const float2*)traj, n_traj,
                                                                 (const float2*)osm, n_osm, ego,
                                                                 out);
    }
}